// Round 3
// baseline (38801.892 us; speedup 1.0000x reference)
//
#include <hip/hip_runtime.h>
#include <cmath>

#define PAD 0
#define INPUT 512
#define HIDDEN 1024
#define LATENT 512
#define BATCH 64
#define TLEN 512
#define G3 3072              // 3*HIDDEN
#define GIN 1024             // INPUT+LATENT
#define NXCD 8
#define TC 64                // t-chunk size (TLEN/TC chunks)

// ---------------------------------------------------------------------------
// K1: zp[b][g] = b_ih[g] + sum_k z[b][k] * W_ih[g][INPUT+k]   (tiny, 0.2 GF)
// ---------------------------------------------------------------------------
__global__ __launch_bounds__(256) void k_zproj(const float* __restrict__ z,
                                               const float* __restrict__ W_ih,
                                               const float* __restrict__ b_ih,
                                               float* __restrict__ zp) {
    __shared__ float zs[LATENT];
    const int b = blockIdx.y;
    const int g = blockIdx.x * 256 + threadIdx.x;
    for (int i = threadIdx.x; i < LATENT; i += 256) zs[i] = z[b * LATENT + i];
    __syncthreads();
    const float* wrow = W_ih + (size_t)g * GIN + INPUT;
    float acc = b_ih[g];
#pragma unroll 4
    for (int k = 0; k < LATENT; k += 4) {
        const float4 w = *reinterpret_cast<const float4*>(wrow + k);
        acc += zs[k] * w.x + zs[k + 1] * w.y + zs[k + 2] * w.z + zs[k + 3] * w.w;
    }
    zp[b * G3 + g] = acc;
}

// ---------------------------------------------------------------------------
// K1b: maskT[t][b] = (x[b][t] == PAD)
// ---------------------------------------------------------------------------
__global__ void k_mask(const int* __restrict__ x, int* __restrict__ maskT) {
    const int t = blockIdx.x;
    const int b = threadIdx.x;
    maskT[t * BATCH + b] = (x[b * TLEN + t] == PAD) ? 1 : 0;
}

// ---------------------------------------------------------------------------
// K2: one t-chunk of x_proj.
// xp[tl][g][b] = zp[b][g] + sum_{k<512} emb[tok(b, t_base+tl)][k] * W_ih[g][k]
// Tiled fp32 GEMM (BM=128 BN=64 BK=32, 256 thr, 8x4/thread) + LDS transpose
// epilogue so the recurrence reads gates coalesced along b.
// grid (G3/64, TC*BATCH/128); local m = tl*64 + b.
// ---------------------------------------------------------------------------
__global__ __launch_bounds__(256) void k_xproj(const int* __restrict__ x,
                                               const float* __restrict__ emb,
                                               const float* __restrict__ W_ih,
                                               const float* __restrict__ zp,
                                               float* __restrict__ xp,
                                               const int t_base) {
    __shared__ float smem[8448];          // As[32][132] | Bs[32][68] ; then Cs[64][132]
    __shared__ int toks[128];
    float (*As)[132] = (float(*)[132])smem;
    float (*Bs)[68]  = (float(*)[68])(smem + 4224);
    float (*Cs)[132] = (float(*)[132])smem;

    const int tid = threadIdx.x;
    const int tx = tid & 15, ty = tid >> 4;
    const int n0 = blockIdx.x * 64;
    const int m0 = blockIdx.y * 128;      // chunk-local
    const int t0 = m0 >> 6;               // chunk-local t of first half-tile
    if (tid < 128) toks[tid] = x[(tid & 63) * TLEN + t_base + t0 + (tid >> 6)];
    __syncthreads();

    float acc[8][4] = {};
    for (int k0 = 0; k0 < INPUT; k0 += 32) {
        for (int idx = tid; idx < 128 * 32; idx += 256) {
            const int i = idx >> 5, kk = idx & 31;
            As[kk][i] = emb[(size_t)toks[i] * INPUT + k0 + kk];
        }
        for (int idx = tid; idx < 64 * 32; idx += 256) {
            const int i = idx >> 5, kk = idx & 31;
            Bs[kk][i] = W_ih[(size_t)(n0 + i) * GIN + k0 + kk];
        }
        __syncthreads();
#pragma unroll
        for (int kk = 0; kk < 32; ++kk) {
            const float4 a0 = *reinterpret_cast<const float4*>(&As[kk][ty * 8]);
            const float4 a1 = *reinterpret_cast<const float4*>(&As[kk][ty * 8 + 4]);
            const float4 bv = *reinterpret_cast<const float4*>(&Bs[kk][tx * 4]);
            const float av[8] = {a0.x, a0.y, a0.z, a0.w, a1.x, a1.y, a1.z, a1.w};
            const float bw[4] = {bv.x, bv.y, bv.z, bv.w};
#pragma unroll
            for (int i = 0; i < 8; ++i)
#pragma unroll
                for (int j = 0; j < 4; ++j) acc[i][j] += av[i] * bw[j];
        }
        __syncthreads();
    }
    // epilogue: add z-projection, transpose through LDS, write xp[tl][g][b]
#pragma unroll
    for (int i = 0; i < 8; ++i) {
        const int b = (ty * 8 + i) & 63;
        const float4 zv = *reinterpret_cast<const float4*>(&zp[(size_t)b * G3 + n0 + tx * 4]);
        Cs[tx * 4 + 0][ty * 8 + i] = acc[i][0] + zv.x;
        Cs[tx * 4 + 1][ty * 8 + i] = acc[i][1] + zv.y;
        Cs[tx * 4 + 2][ty * 8 + i] = acc[i][2] + zv.z;
        Cs[tx * 4 + 3][ty * 8 + i] = acc[i][3] + zv.w;
    }
    __syncthreads();
#pragma unroll
    for (int it = 0; it < 32; ++it) {
        const int idx = it * 256 + tid;   // 0..8191 over [tt][gl][b]
        const int b = idx & 63;
        const int gl = (idx >> 6) & 63;
        const int tt = idx >> 12;
        xp[(size_t)(t0 + tt) * (G3 * BATCH) + (size_t)(n0 + gl) * BATCH + b] =
            Cs[gl][tt * 64 + b];
    }
}

// ---------------------------------------------------------------------------
// K3: one GRU step.  256 blocks (j-tile of 4) x 256 threads (wave=jl, lane=b).
//  - W_hh slice (12 rows, 48KB) staged to LDS once per launch (L2-resident).
//  - h_prev staged to LDS in 8 chunks of [64b][128k], double-buffered,
//    XOR-swizzled (source-side swizzle + matching swizzled read) so
//    ds_read_b128 runs at the 8-words-per-bank floor.
//  - h replicated per-XCD (read replica bid&7, write all 8): staging reads
//    hit XCD-local L2 instead of LLC.
//  - gate preactivations / hold / mask prefetched at entry (coalesced).
// ---------------------------------------------------------------------------
__global__ __launch_bounds__(256) void k_gru_step(
    const float* __restrict__ xp_t,    // [G3][64]
    const float* __restrict__ hrep_r,  // [8][64][1024]
    float* __restrict__ hrep_w,        // [8][64][1024]
    float* __restrict__ hs_t,          // [64][1024]  (chunk-local, for K4)
    const float* __restrict__ Whh,
    const float* __restrict__ bhh,
    const int* __restrict__ maskt,     // [64]
    const int t) {
    __shared__ float Ws[12 * 1024];        // 48 KB
    __shared__ float Ab[2 * 64 * 128];     // 64 KB double-buffered h chunks

    const int tid = threadIdx.x;
    const int jl = tid >> 6;               // wave id 0..3 (wave-uniform)
    const int b = tid & 63;
    const int j0 = blockIdx.x * 4;
    const int j = j0 + jl;

    // prefetch epilogue operands (coalesced along b)
    const float xr = xp_t[(size_t)j * BATCH + b];
    const float xu = xp_t[(size_t)(HIDDEN + j) * BATCH + b];
    const float xn = xp_t[(size_t)(2 * HIDDEN + j) * BATCH + b];
    const float* hrd = hrep_r + (size_t)(blockIdx.x & (NXCD - 1)) * (BATCH * HIDDEN);
    const float hold = (t > 0) ? hrd[b * HIDDEN + j] : 0.f;
    const int msk = maskt[b];
    const float br = bhh[j], bu = bhh[HIDDEN + j], bn = bhh[2 * HIDDEN + j];

    // stage W_hh slice: Ws row = gate*4 + jl_row  ->  Whh row gate*1024 + j0 + jl_row
#pragma unroll
    for (int q = 0; q < 12; ++q) {
        const int f4 = q * 256 + tid;      // 3072 float4s
        const int row = f4 >> 8;           // 256 float4 per Ws row
        const int col = (f4 & 255) * 4;
        const int g = (row >> 2) * HIDDEN + j0 + (row & 3);
        *reinterpret_cast<float4*>(&Ws[row * 1024 + col]) =
            *reinterpret_cast<const float4*>(&Whh[(size_t)g * HIDDEN + col]);
    }

    float ar0 = 0.f, ar1 = 0.f, au0 = 0.f, au1 = 0.f, an0 = 0.f, an1 = 0.f;

    if (t > 0) {
        float4 st[8];
        // load chunk c of h into regs: source XOR-swizzled within each 512B row
        auto ldchunk = [&](int c, float4* r) {
#pragma unroll
            for (int q = 0; q < 8; ++q) {
                const int flat = q * 256 + tid;      // 0..2047 float4s
                const int bb = flat >> 5;            // h row
                const int kc = (flat & 31) * 4;      // word col 0..124
                const int ks = kc ^ ((bb & 7) << 2); // source swizzle
                r[q] = *reinterpret_cast<const float4*>(
                    &hrd[(size_t)bb * HIDDEN + c * 128 + ks]);
            }
        };
        // store regs to LDS linearly (dest stays linear row-major)
        auto stchunk = [&](int buf, const float4* r) {
            float* A = Ab + buf * (64 * 128);
#pragma unroll
            for (int q = 0; q < 8; ++q) {
                const int flat = q * 256 + tid;
                *reinterpret_cast<float4*>(&A[flat * 4]) = r[q];
            }
        };

        ldchunk(0, st);
        stchunk(0, st);
        __syncthreads();                 // also covers Ws staging

        const int swz = (b & 7) << 2;
        const float* wrb = Ws + (0 * 4 + jl) * 1024;
        const float* wub = Ws + (4 + jl) * 1024;
        const float* wnb = Ws + (8 + jl) * 1024;

        for (int c = 0; c < 8; ++c) {
            if (c < 7) ldchunk(c + 1, st);   // issue next-chunk loads early
            const float* A = Ab + (c & 1) * (64 * 128) + b * 128;
            const float* wr = wrb + c * 128;
            const float* wu = wub + c * 128;
            const float* wn = wnb + c * 128;
#pragma unroll
            for (int kk = 0; kk < 128; kk += 8) {
                const float4 h0 = *reinterpret_cast<const float4*>(&A[kk ^ swz]);
                const float4 h1 = *reinterpret_cast<const float4*>(&A[(kk + 4) ^ swz]);
                const float4 r0 = *reinterpret_cast<const float4*>(&wr[kk]);
                const float4 r1 = *reinterpret_cast<const float4*>(&wr[kk + 4]);
                const float4 u0 = *reinterpret_cast<const float4*>(&wu[kk]);
                const float4 u1 = *reinterpret_cast<const float4*>(&wu[kk + 4]);
                const float4 n0v = *reinterpret_cast<const float4*>(&wn[kk]);
                const float4 n1v = *reinterpret_cast<const float4*>(&wn[kk + 4]);
                ar0 += h0.x * r0.x + h0.y * r0.y + h0.z * r0.z + h0.w * r0.w;
                ar1 += h1.x * r1.x + h1.y * r1.y + h1.z * r1.z + h1.w * r1.w;
                au0 += h0.x * u0.x + h0.y * u0.y + h0.z * u0.z + h0.w * u0.w;
                au1 += h1.x * u1.x + h1.y * u1.y + h1.z * u1.z + h1.w * u1.w;
                an0 += h0.x * n0v.x + h0.y * n0v.y + h0.z * n0v.z + h0.w * n0v.w;
                an1 += h1.x * n1v.x + h1.y * n1v.y + h1.z * n1v.z + h1.w * n1v.w;
            }
            if (c < 7) {
                stchunk((c + 1) & 1, st);    // write-late after compute
                __syncthreads();
            }
        }
    }

    const float hr = ar0 + ar1 + br;
    const float hu = au0 + au1 + bu;
    const float hn = an0 + an1 + bn;
    const float r = 1.f / (1.f + expf(-(xr + hr)));
    const float u = 1.f / (1.f + expf(-(xu + hu)));
    const float n = tanhf(xn + r * hn);
    float hnew = (1.f - u) * n + u * hold;
    if (msk) hnew = hold;

#pragma unroll
    for (int rep = 0; rep < NXCD; ++rep)
        hrep_w[(size_t)rep * (BATCH * HIDDEN) + (size_t)b * HIDDEN + j] = hnew;
    hs_t[(size_t)b * HIDDEN + j] = hnew;
}

// ---------------------------------------------------------------------------
// K4: one t-chunk of the output projection.
// out[b][t_base+tl][o] = tanh(b_out[o] + sum_k cat[ml][k] * W_out[o][k])
// cat[ml] = [ hs[ml][0:1024] | emb[tok][0:512] ],  ml = tl*64 + b (chunk-local)
// grid (INPUT/64, TC*BATCH/128)
// ---------------------------------------------------------------------------
__global__ __launch_bounds__(256) void k_out(const float* __restrict__ hs,
                                             const int* __restrict__ x,
                                             const float* __restrict__ emb,
                                             const float* __restrict__ W_out,
                                             const float* __restrict__ b_out,
                                             float* __restrict__ out,
                                             const int t_base) {
    __shared__ float As[32][132];
    __shared__ float Bs[32][68];
    __shared__ int toks[128];
    const int tid = threadIdx.x;
    const int tx = tid & 15, ty = tid >> 4;
    const int n0 = blockIdx.x * 64;
    const int m0 = blockIdx.y * 128;      // chunk-local
    const int t0 = m0 >> 6;               // chunk-local
    if (tid < 128) toks[tid] = x[(tid & 63) * TLEN + t_base + t0 + (tid >> 6)];
    __syncthreads();

    float acc[8][4] = {};
    for (int k0 = 0; k0 < HIDDEN + INPUT; k0 += 32) {
        if (k0 < HIDDEN) {
            for (int idx = tid; idx < 128 * 32; idx += 256) {
                const int i = idx >> 5, kk = idx & 31;
                As[kk][i] = hs[(size_t)(m0 + i) * HIDDEN + k0 + kk];
            }
        } else {
            for (int idx = tid; idx < 128 * 32; idx += 256) {
                const int i = idx >> 5, kk = idx & 31;
                As[kk][i] = emb[(size_t)toks[i] * INPUT + (k0 - HIDDEN) + kk];
            }
        }
        for (int idx = tid; idx < 64 * 32; idx += 256) {
            const int i = idx >> 5, kk = idx & 31;
            Bs[kk][i] = W_out[(size_t)(n0 + i) * (HIDDEN + INPUT) + k0 + kk];
        }
        __syncthreads();
#pragma unroll
        for (int kk = 0; kk < 32; ++kk) {
            const float4 a0 = *reinterpret_cast<const float4*>(&As[kk][ty * 8]);
            const float4 a1 = *reinterpret_cast<const float4*>(&As[kk][ty * 8 + 4]);
            const float4 bv = *reinterpret_cast<const float4*>(&Bs[kk][tx * 4]);
            const float av[8] = {a0.x, a0.y, a0.z, a0.w, a1.x, a1.y, a1.z, a1.w};
            const float bw[4] = {bv.x, bv.y, bv.z, bv.w};
#pragma unroll
            for (int i = 0; i < 8; ++i)
#pragma unroll
                for (int j = 0; j < 4; ++j) acc[i][j] += av[i] * bw[j];
        }
        __syncthreads();
    }
    const float4 bo = *reinterpret_cast<const float4*>(&b_out[n0 + tx * 4]);
    const float bof[4] = {bo.x, bo.y, bo.z, bo.w};
#pragma unroll
    for (int i = 0; i < 8; ++i) {
        const int ml = m0 + ty * 8 + i;
        const int b = ml & 63;
        const int t = t_base + (ml >> 6);
        float4 o;
        o.x = tanhf(acc[i][0] + bof[0]);
        o.y = tanhf(acc[i][1] + bof[1]);
        o.z = tanhf(acc[i][2] + bof[2]);
        o.w = tanhf(acc[i][3] + bof[3]);
        *reinterpret_cast<float4*>(
            &out[(size_t)b * (TLEN * INPUT) + (size_t)t * INPUT + n0 + tx * 4]) = o;
    }
}

// ---------------------------------------------------------------------------
// Workspace (fp32), chunked to ~72 MB total:
//   xp    : [TC=64][3072 g][64 b]   50.3 MB  (one t-chunk of x_proj)
//   hsbuf : [TC*64 m][1024]         16.8 MB  (one t-chunk of hidden states)
//   hrepA/B : [8][64][1024]       2x 2.1 MB  (per-XCD h replicas, ping-pong)
//   zp    : [64][3072]               0.8 MB
//   maskT : [512][64] int            0.13 MB
// ---------------------------------------------------------------------------
extern "C" void kernel_launch(void* const* d_in, const int* in_sizes, int n_in,
                              void* d_out, int out_size, void* d_ws, size_t ws_size,
                              hipStream_t stream) {
    const int* x = (const int*)d_in[0];
    const float* z = (const float*)d_in[1];
    const float* emb = (const float*)d_in[2];
    const float* W_ih = (const float*)d_in[3];
    const float* b_ih = (const float*)d_in[4];
    const float* W_hh = (const float*)d_in[5];
    const float* b_hh = (const float*)d_in[6];
    const float* W_out = (const float*)d_in[7];
    const float* b_out = (const float*)d_in[8];
    float* out = (float*)d_out;

    float* xp = (float*)d_ws;                               // [TC][3072][64]
    float* hsbuf = xp + (size_t)TC * G3 * BATCH;            // [TC*64][1024]
    float* hrepA = hsbuf + (size_t)TC * BATCH * HIDDEN;     // [8][64][1024]
    float* hrepB = hrepA + (size_t)NXCD * BATCH * HIDDEN;
    float* zp = hrepB + (size_t)NXCD * BATCH * HIDDEN;      // [64][3072]
    int* maskT = (int*)(zp + (size_t)BATCH * G3);           // [512][64]

    k_zproj<<<dim3(G3 / 256, BATCH), 256, 0, stream>>>(z, W_ih, b_ih, zp);
    k_mask<<<TLEN, BATCH, 0, stream>>>(x, maskT);

    for (int c = 0; c < TLEN / TC; ++c) {
        const int tb = c * TC;
        k_xproj<<<dim3(G3 / 64, TC * BATCH / 128), 256, 0, stream>>>(
            x, emb, W_ih, zp, xp, tb);
        for (int tl = 0; tl < TC; ++tl) {
            const int t = tb + tl;
            const float* hr = (t & 1) ? hrepA : hrepB;   // t=0 reads B (unused)
            float* hw = (t & 1) ? hrepB : hrepA;
            k_gru_step<<<256, 256, 0, stream>>>(
                xp + (size_t)tl * G3 * BATCH, hr, hw,
                hsbuf + (size_t)tl * BATCH * HIDDEN,
                W_hh, b_hh, maskT + t * BATCH, t);
        }
        k_out<<<dim3(INPUT / 64, TC * BATCH / 128), 256, 0, stream>>>(
            hsbuf, x, emb, W_out, b_out, out, tb);
    }
}

// Round 5
// 36388.245 us; speedup vs baseline: 1.0663x; 1.0663x over previous
//
#include <hip/hip_runtime.h>
#include <hip/hip_cooperative_groups.h>
#include <cmath>

namespace cg = cooperative_groups;

#define PAD 0
#define INPUT 512
#define HIDDEN 1024
#define LATENT 512
#define BATCH 64
#define TLEN 512
#define G3 3072              // 3*HIDDEN
#define GIN 1024             // INPUT+LATENT
#define TC 64                // t-chunk size (TLEN/TC chunks)
#define KC 32                // k-chunk of the h-staging buffer

// ---------------------------------------------------------------------------
// K1: zp[b][g] = b_ih[g] + sum_k z[b][k] * W_ih[g][INPUT+k]   (tiny, 0.2 GF)
// ---------------------------------------------------------------------------
__global__ __launch_bounds__(256) void k_zproj(const float* __restrict__ z,
                                               const float* __restrict__ W_ih,
                                               const float* __restrict__ b_ih,
                                               float* __restrict__ zp) {
    __shared__ float zs[LATENT];
    const int b = blockIdx.y;
    const int g = blockIdx.x * 256 + threadIdx.x;
    for (int i = threadIdx.x; i < LATENT; i += 256) zs[i] = z[b * LATENT + i];
    __syncthreads();
    const float* wrow = W_ih + (size_t)g * GIN + INPUT;
    float acc = b_ih[g];
#pragma unroll 4
    for (int k = 0; k < LATENT; k += 4) {
        const float4 w = *reinterpret_cast<const float4*>(wrow + k);
        acc += zs[k] * w.x + zs[k + 1] * w.y + zs[k + 2] * w.z + zs[k + 3] * w.w;
    }
    zp[b * G3 + g] = acc;
}

// ---------------------------------------------------------------------------
// K1b: maskT[t][b] = (x[b][t] == PAD)
// ---------------------------------------------------------------------------
__global__ void k_mask(const int* __restrict__ x, int* __restrict__ maskT) {
    const int t = blockIdx.x;
    const int b = threadIdx.x;
    maskT[t * BATCH + b] = (x[b * TLEN + t] == PAD) ? 1 : 0;
}

// ---------------------------------------------------------------------------
// K2: one t-chunk of x_proj (proven in round 3).
// xp[tl][g][b] = zp[b][g] + sum_{k<512} emb[tok(b, t_base+tl)][k] * W_ih[g][k]
// ---------------------------------------------------------------------------
__global__ __launch_bounds__(256) void k_xproj(const int* __restrict__ x,
                                               const float* __restrict__ emb,
                                               const float* __restrict__ W_ih,
                                               const float* __restrict__ zp,
                                               float* __restrict__ xp,
                                               const int t_base) {
    __shared__ float smem[8448];          // As[32][132] | Bs[32][68] ; then Cs[64][132]
    __shared__ int toks[128];
    float (*As)[132] = (float(*)[132])smem;
    float (*Bs)[68]  = (float(*)[68])(smem + 4224);
    float (*Cs)[132] = (float(*)[132])smem;

    const int tid = threadIdx.x;
    const int tx = tid & 15, ty = tid >> 4;
    const int n0 = blockIdx.x * 64;
    const int m0 = blockIdx.y * 128;      // chunk-local
    const int t0 = m0 >> 6;
    if (tid < 128) toks[tid] = x[(tid & 63) * TLEN + t_base + t0 + (tid >> 6)];
    __syncthreads();

    float acc[8][4] = {};
    for (int k0 = 0; k0 < INPUT; k0 += 32) {
        for (int idx = tid; idx < 128 * 32; idx += 256) {
            const int i = idx >> 5, kk = idx & 31;
            As[kk][i] = emb[(size_t)toks[i] * INPUT + k0 + kk];
        }
        for (int idx = tid; idx < 64 * 32; idx += 256) {
            const int i = idx >> 5, kk = idx & 31;
            Bs[kk][i] = W_ih[(size_t)(n0 + i) * GIN + k0 + kk];
        }
        __syncthreads();
#pragma unroll
        for (int kk = 0; kk < 32; ++kk) {
            const float4 a0 = *reinterpret_cast<const float4*>(&As[kk][ty * 8]);
            const float4 a1 = *reinterpret_cast<const float4*>(&As[kk][ty * 8 + 4]);
            const float4 bv = *reinterpret_cast<const float4*>(&Bs[kk][tx * 4]);
            const float av[8] = {a0.x, a0.y, a0.z, a0.w, a1.x, a1.y, a1.z, a1.w};
            const float bw[4] = {bv.x, bv.y, bv.z, bv.w};
#pragma unroll
            for (int i = 0; i < 8; ++i)
#pragma unroll
                for (int j = 0; j < 4; ++j) acc[i][j] += av[i] * bw[j];
        }
        __syncthreads();
    }
#pragma unroll
    for (int i = 0; i < 8; ++i) {
        const int b = (ty * 8 + i) & 63;
        const float4 zv = *reinterpret_cast<const float4*>(&zp[(size_t)b * G3 + n0 + tx * 4]);
        Cs[tx * 4 + 0][ty * 8 + i] = acc[i][0] + zv.x;
        Cs[tx * 4 + 1][ty * 8 + i] = acc[i][1] + zv.y;
        Cs[tx * 4 + 2][ty * 8 + i] = acc[i][2] + zv.z;
        Cs[tx * 4 + 3][ty * 8 + i] = acc[i][3] + zv.w;
    }
    __syncthreads();
#pragma unroll
    for (int it = 0; it < 32; ++it) {
        const int idx = it * 256 + tid;   // 0..8191 over [tt][gl][b]
        const int b = idx & 63;
        const int gl = (idx >> 6) & 63;
        const int tt = idx >> 12;
        xp[(size_t)(t0 + tt) * (G3 * BATCH) + (size_t)(n0 + gl) * BATCH + b] =
            Cs[gl][tt * 64 + b];
    }
}

// ---------------------------------------------------------------------------
// Shared GRU-step body.  Block = 4 waves; wave jl owns column j = j0+jl;
// lane = b.  Ws: 12 rows (3 gates x 4 j) staged by caller.  Ab: [64][KC=32]
// single-buffer h chunk, reg-carried prefetch, source-XOR-swizzled so the
// per-lane ds_read_b128 spreads over 8 distinct 16B slots (round-3-proven).
// ---------------------------------------------------------------------------
__device__ __forceinline__ void stage_Ws(const float* __restrict__ Whh,
                                         float* Ws, int tid, int j0) {
#pragma unroll
    for (int q = 0; q < 12; ++q) {
        const int f4 = q * 256 + tid;      // 3072 float4s
        const int row = f4 >> 8;           // 256 float4 per Ws row
        const int col = (f4 & 255) * 4;
        const int g = (row >> 2) * HIDDEN + j0 + (row & 3);
        *reinterpret_cast<float4*>(&Ws[row * 1024 + col]) =
            *reinterpret_cast<const float4*>(&Whh[(size_t)g * HIDDEN + col]);
    }
}

__device__ __forceinline__ void gru_step(
    const float* __restrict__ xpt,     // [G3][64]
    const float* __restrict__ hin,     // [64][1024]  (unused at t==0)
    float* __restrict__ hout,          // [64][1024]
    float* __restrict__ hsl,           // [64][1024]  chunk-local hs slice
    const float* Ws, float* Ab,
    const int* __restrict__ maskt,
    float br, float bu, float bn,
    int t, int tid, int jl, int b, int j) {

    const float xr = xpt[(size_t)j * BATCH + b];
    const float xu = xpt[(size_t)(HIDDEN + j) * BATCH + b];
    const float xn = xpt[(size_t)(2 * HIDDEN + j) * BATCH + b];
    const int msk = maskt[b];
    const float hold = (t > 0) ? hin[(size_t)b * HIDDEN + j] : 0.f;

    float ar0 = 0.f, ar1 = 0.f, au0 = 0.f, au1 = 0.f, an0 = 0.f, an1 = 0.f;

    if (t > 0) {
        float4 st[2];
        auto ldchunk = [&](int c) {
#pragma unroll
            for (int q = 0; q < 2; ++q) {
                const int flat = q * 256 + tid;       // 0..511 float4
                const int bb = flat >> 3;             // 8 f4 per 32-float row
                const int kc = (flat & 7) * 4;        // 0,4,...,28
                const int ks = kc ^ ((bb & 7) << 2);  // source swizzle
                st[q] = *reinterpret_cast<const float4*>(
                    &hin[(size_t)bb * HIDDEN + c * KC + ks]);
            }
        };

        ldchunk(0);
        const int swz = (b & 7) << 2;
        const float* wrb = Ws + jl * 1024;
        const float* wub = Ws + (4 + jl) * 1024;
        const float* wnb = Ws + (8 + jl) * 1024;

        for (int c = 0; c < HIDDEN / KC; ++c) {
            __syncthreads();               // prior chunk's reads done (also Ws)
#pragma unroll
            for (int q = 0; q < 2; ++q) {  // store regs -> Ab (linear dest)
                const int flat = q * 256 + tid;
                *reinterpret_cast<float4*>(&Ab[flat * 4]) = st[q];
            }
            if (c < HIDDEN / KC - 1) ldchunk(c + 1);  // overlap next global loads
            __syncthreads();               // chunk visible
            const float* A = Ab + b * KC;
            const float* wr = wrb + c * KC;
            const float* wu = wub + c * KC;
            const float* wn = wnb + c * KC;
#pragma unroll
            for (int kk = 0; kk < KC; kk += 8) {
                const float4 h0 = *reinterpret_cast<const float4*>(&A[kk ^ swz]);
                const float4 h1 = *reinterpret_cast<const float4*>(&A[(kk + 4) ^ swz]);
                const float4 r0 = *reinterpret_cast<const float4*>(&wr[kk]);
                const float4 r1 = *reinterpret_cast<const float4*>(&wr[kk + 4]);
                const float4 u0 = *reinterpret_cast<const float4*>(&wu[kk]);
                const float4 u1 = *reinterpret_cast<const float4*>(&wu[kk + 4]);
                const float4 n0v = *reinterpret_cast<const float4*>(&wn[kk]);
                const float4 n1v = *reinterpret_cast<const float4*>(&wn[kk + 4]);
                ar0 += h0.x * r0.x + h0.y * r0.y + h0.z * r0.z + h0.w * r0.w;
                ar1 += h1.x * r1.x + h1.y * r1.y + h1.z * r1.z + h1.w * r1.w;
                au0 += h0.x * u0.x + h0.y * u0.y + h0.z * u0.z + h0.w * u0.w;
                au1 += h1.x * u1.x + h1.y * u1.y + h1.z * u1.z + h1.w * u1.w;
                an0 += h0.x * n0v.x + h0.y * n0v.y + h0.z * n0v.z + h0.w * n0v.w;
                an1 += h1.x * n1v.x + h1.y * n1v.y + h1.z * n1v.z + h1.w * n1v.w;
            }
        }
    }

    const float hr = ar0 + ar1 + br;
    const float hu = au0 + au1 + bu;
    const float hn = an0 + an1 + bn;
    const float r = 1.f / (1.f + expf(-(xr + hr)));
    const float u = 1.f / (1.f + expf(-(xu + hu)));
    const float n = tanhf(xn + r * hn);
    float hnew = (1.f - u) * n + u * hold;
    if (msk) hnew = hold;

    hout[(size_t)b * HIDDEN + j] = hnew;
    hsl[(size_t)b * HIDDEN + j] = hnew;
}

// ---------------------------------------------------------------------------
// K3a: persistent cooperative GRU chunk — TC steps in ONE launch.
// 256 blocks x 256 threads, 56 KB LDS (Ws 48K once per chunk + Ab 8K).
// step t reads buf[(t+1)&1], writes buf[t&1]; grid.sync() per step.
// ---------------------------------------------------------------------------
__global__ __launch_bounds__(256) void k_gru_chunk(
    const float* __restrict__ xp,      // [TC][G3][64]
    float* __restrict__ buf0,          // [64][1024]
    float* __restrict__ buf1,          // [64][1024]
    float* __restrict__ hsbuf,         // [TC][64][1024]
    const float* __restrict__ Whh,
    const float* __restrict__ bhh,
    const int* __restrict__ maskT,     // [TLEN][64]
    const int t_base) {
    __shared__ float Ws[12 * 1024];        // 48 KB
    __shared__ float Ab[64 * KC];          //  8 KB
    cg::grid_group grid = cg::this_grid();

    const int tid = threadIdx.x;
    const int jl = tid >> 6;
    const int b = tid & 63;
    const int j0 = blockIdx.x * 4;
    const int j = j0 + jl;

    stage_Ws(Whh, Ws, tid, j0);            // once per TC steps
    const float br = bhh[j], bu = bhh[HIDDEN + j], bn = bhh[2 * HIDDEN + j];

    for (int tl = 0; tl < TC; ++tl) {
        const int t = t_base + tl;
        const float* hin = (t & 1) ? buf0 : buf1;
        float* hout = (t & 1) ? buf1 : buf0;
        gru_step(xp + (size_t)tl * (G3 * BATCH), hin, hout,
                 hsbuf + (size_t)tl * (BATCH * HIDDEN),
                 Ws, Ab, maskT + t * BATCH, br, bu, bn, t, tid, jl, b, j);
        grid.sync();                       // device-scope release/acquire
    }
}

// ---------------------------------------------------------------------------
// K3b: fallback per-step kernel (round-3-proven path, same body).
// ---------------------------------------------------------------------------
__global__ __launch_bounds__(256) void k_gru_step_kern(
    const float* __restrict__ xpt,     // [G3][64]
    const float* __restrict__ hin,
    float* __restrict__ hout,
    float* __restrict__ hsl,
    const float* __restrict__ Whh,
    const float* __restrict__ bhh,
    const int* __restrict__ maskt,     // [64]
    const int t) {
    __shared__ float Ws[12 * 1024];
    __shared__ float Ab[64 * KC];
    const int tid = threadIdx.x;
    const int jl = tid >> 6;
    const int b = tid & 63;
    const int j0 = blockIdx.x * 4;
    const int j = j0 + jl;
    stage_Ws(Whh, Ws, tid, j0);
    const float br = bhh[j], bu = bhh[HIDDEN + j], bn = bhh[2 * HIDDEN + j];
    gru_step(xpt, hin, hout, hsl, Ws, Ab, maskt, br, bu, bn, t, tid, jl, b, j);
}

// ---------------------------------------------------------------------------
// K4: one t-chunk of the output projection (proven in round 3).
// ---------------------------------------------------------------------------
__global__ __launch_bounds__(256) void k_out(const float* __restrict__ hs,
                                             const int* __restrict__ x,
                                             const float* __restrict__ emb,
                                             const float* __restrict__ W_out,
                                             const float* __restrict__ b_out,
                                             float* __restrict__ out,
                                             const int t_base) {
    __shared__ float As[32][132];
    __shared__ float Bs[32][68];
    __shared__ int toks[128];
    const int tid = threadIdx.x;
    const int tx = tid & 15, ty = tid >> 4;
    const int n0 = blockIdx.x * 64;
    const int m0 = blockIdx.y * 128;
    const int t0 = m0 >> 6;
    if (tid < 128) toks[tid] = x[(tid & 63) * TLEN + t_base + t0 + (tid >> 6)];
    __syncthreads();

    float acc[8][4] = {};
    for (int k0 = 0; k0 < HIDDEN + INPUT; k0 += 32) {
        if (k0 < HIDDEN) {
            for (int idx = tid; idx < 128 * 32; idx += 256) {
                const int i = idx >> 5, kk = idx & 31;
                As[kk][i] = hs[(size_t)(m0 + i) * HIDDEN + k0 + kk];
            }
        } else {
            for (int idx = tid; idx < 128 * 32; idx += 256) {
                const int i = idx >> 5, kk = idx & 31;
                As[kk][i] = emb[(size_t)toks[i] * INPUT + (k0 - HIDDEN) + kk];
            }
        }
        for (int idx = tid; idx < 64 * 32; idx += 256) {
            const int i = idx >> 5, kk = idx & 31;
            Bs[kk][i] = W_out[(size_t)(n0 + i) * (HIDDEN + INPUT) + k0 + kk];
        }
        __syncthreads();
#pragma unroll
        for (int kk = 0; kk < 32; ++kk) {
            const float4 a0 = *reinterpret_cast<const float4*>(&As[kk][ty * 8]);
            const float4 a1 = *reinterpret_cast<const float4*>(&As[kk][ty * 8 + 4]);
            const float4 bv = *reinterpret_cast<const float4*>(&Bs[kk][tx * 4]);
            const float av[8] = {a0.x, a0.y, a0.z, a0.w, a1.x, a1.y, a1.z, a1.w};
            const float bw[4] = {bv.x, bv.y, bv.z, bv.w};
#pragma unroll
            for (int i = 0; i < 8; ++i)
#pragma unroll
                for (int j = 0; j < 4; ++j) acc[i][j] += av[i] * bw[j];
        }
        __syncthreads();
    }
    const float4 bo = *reinterpret_cast<const float4*>(&b_out[n0 + tx * 4]);
    const float bof[4] = {bo.x, bo.y, bo.z, bo.w};
#pragma unroll
    for (int i = 0; i < 8; ++i) {
        const int ml = m0 + ty * 8 + i;
        const int b = ml & 63;
        const int t = t_base + (ml >> 6);
        float4 o;
        o.x = tanhf(acc[i][0] + bof[0]);
        o.y = tanhf(acc[i][1] + bof[1]);
        o.z = tanhf(acc[i][2] + bof[2]);
        o.w = tanhf(acc[i][3] + bof[3]);
        *reinterpret_cast<float4*>(
            &out[(size_t)b * (TLEN * INPUT) + (size_t)t * INPUT + n0 + tx * 4]) = o;
    }
}

// ---------------------------------------------------------------------------
// Workspace (fp32), ~68 MB total:
//   xp    : [TC=64][3072 g][64 b]   50.3 MB
//   hsbuf : [TC][64][1024]          16.8 MB
//   buf0/1: [64][1024]            2x 0.26 MB
//   zp    : [64][3072]               0.8 MB
//   maskT : [512][64] int            0.13 MB
// ---------------------------------------------------------------------------
extern "C" void kernel_launch(void* const* d_in, const int* in_sizes, int n_in,
                              void* d_out, int out_size, void* d_ws, size_t ws_size,
                              hipStream_t stream) {
    const int* x = (const int*)d_in[0];
    const float* z = (const float*)d_in[1];
    const float* emb = (const float*)d_in[2];
    const float* W_ih = (const float*)d_in[3];
    const float* b_ih = (const float*)d_in[4];
    const float* W_hh = (const float*)d_in[5];
    const float* b_hh = (const float*)d_in[6];
    const float* W_out = (const float*)d_in[7];
    const float* b_out = (const float*)d_in[8];
    float* out = (float*)d_out;

    float* xp = (float*)d_ws;                               // [TC][3072][64]
    float* hsbuf = xp + (size_t)TC * G3 * BATCH;            // [TC][64][1024]
    float* buf0 = hsbuf + (size_t)TC * BATCH * HIDDEN;      // [64][1024]
    float* buf1 = buf0 + (size_t)BATCH * HIDDEN;
    float* zp = buf1 + (size_t)BATCH * HIDDEN;              // [64][3072]
    int* maskT = (int*)(zp + (size_t)BATCH * G3);           // [512][64]

    // Capture-safe, deterministic host query: can 256 coop blocks co-reside?
    int nb = 0;
    hipError_t qe = hipOccupancyMaxActiveBlocksPerMultiprocessor(
        &nb, k_gru_chunk, 256, 0);
    const bool coop_ok = (qe == hipSuccess && nb >= 1);

    k_zproj<<<dim3(G3 / 256, BATCH), 256, 0, stream>>>(z, W_ih, b_ih, zp);
    k_mask<<<TLEN, BATCH, 0, stream>>>(x, maskT);

    for (int c = 0; c < TLEN / TC; ++c) {
        const int tb = c * TC;
        k_xproj<<<dim3(G3 / 64, TC * BATCH / 128), 256, 0, stream>>>(
            x, emb, W_ih, zp, xp, tb);

        bool done = false;
        if (coop_ok) {
            int tb_arg = tb;
            void* args[] = {(void*)&xp, (void*)&buf0, (void*)&buf1, (void*)&hsbuf,
                            (void*)&W_hh, (void*)&b_hh, (void*)&maskT, (void*)&tb_arg};
            hipError_t le = hipLaunchCooperativeKernel(
                (const void*)k_gru_chunk, dim3(256), dim3(256), args, 0, stream);
            done = (le == hipSuccess);
        }
        if (!done) {
            for (int tl = 0; tl < TC; ++tl) {
                const int t = tb + tl;
                const float* hin = (t & 1) ? buf0 : buf1;
                float* hout = (t & 1) ? buf1 : buf0;
                k_gru_step_kern<<<256, 256, 0, stream>>>(
                    xp + (size_t)tl * G3 * BATCH, hin, hout,
                    hsbuf + (size_t)tl * BATCH * HIDDEN,
                    W_hh, b_hh, maskT + t * BATCH, t);
            }
        }

        k_out<<<dim3(INPUT / 64, TC * BATCH / 128), 256, 0, stream>>>(
            hsbuf, x, emb, W_out, b_out, out, tb);
    }
}